// Round 4
// baseline (61.136 us; speedup 1.0000x reference)
//
#include <hip/hip_runtime.h>
#include <math.h>

// Problem constants
#define B_SZ   8192
#define D_IN   512
#define M0_N   128
#define M1_N   128
#define K_TOP  8
#define H_DIM  128
#define ROWS   16          // batch rows per block
#define XPITCH 520         // padded LDS row pitch (floats); 520%32=8 -> banks spread

// ---------------------------------------------------------------------------
// Wave-parallel iterative top-k, jax.lax.top_k semantics (descending value,
// ties -> lowest index). NCH*64 candidates; lane 0 writes out_idx.
template<int NCH>
__device__ __forceinline__ void wave_topk(const float* __restrict__ base,
                                          int stride, int k, int* out_idx,
                                          int lane) {
  float v[NCH];
#pragma unroll
  for (int t = 0; t < NCH; ++t) v[t] = base[(t * 64 + lane) * stride];
  for (int r = 0; r < k; ++r) {
    float bv = -INFINITY;
    int bd = 0x7fffffff;
#pragma unroll
    for (int t = 0; t < NCH; ++t) {
      if (v[t] > bv) { bv = v[t]; bd = t * 64 + lane; }
    }
#pragma unroll
    for (int m = 1; m < 64; m <<= 1) {
      float ov = __shfl_xor(bv, m, 64);
      int   od = __shfl_xor(bd, m, 64);
      if (ov > bv || (ov == bv && od < bd)) { bv = ov; bd = od; }
    }
    if (lane == 0) out_idx[r] = bd;
    if ((bd & 63) == lane) {
      const int tw = bd >> 6;
#pragma unroll
      for (int tt = 0; tt < NCH; ++tt)
        if (tt == tw) v[tt] = -INFINITY;
    }
  }
}

// ---------------------------------------------------------------------------
// Single fused kernel: per-block inline routing + layer0(16 slots) + layer1 +
// sigmoid. Block = 16 rows x 256 threads; thread (g=tid&31, rl=tid>>5) owns
// hidden units 4g..4g+3 of rows {2rl, 2rl+1}. Reduce over 32 g-lanes via
// shfl_xor(1..16) within each 32-lane half-wave.
__global__ __launch_bounds__(256)
void fused_all(const float* __restrict__ x,
               const int* __restrict__ task_id_p,
               const float* __restrict__ emb0,
               const float* __restrict__ emb1,
               const float* __restrict__ emb_out,
               const float* __restrict__ W1_0, const float* __restrict__ b1_0,
               const float* __restrict__ W2_0, const float* __restrict__ b2_0,
               const float* __restrict__ W1_1, const float* __restrict__ b1_1,
               const float* __restrict__ W2_1, const float* __restrict__ b2_1,
               float* __restrict__ out) {
  __shared__ float xt[ROWS * XPITCH];   // full x tile, padded
  __shared__ float tile[16 * 18];       // layer-0 outputs [slot][row]
  __shared__ int   s_m1[2];
  __shared__ int   s_m0[16];
  __shared__ int   s_cols[16 * 8];

  const int tid  = threadIdx.x;
  const int lane = tid & 63;
  const int wid  = tid >> 6;
  const int task = task_id_p[0];
  const int rowbase = blockIdx.x * ROWS;

  // ---- issue coalesced x stage into regs (latency overlapped w/ routing A)
  float4 xr[8];
#pragma unroll
  for (int i = 0; i < 8; ++i) {
    const int e = tid + i * 256;
    xr[i] = *(const float4*)(x + (size_t)(rowbase + (e >> 7)) * D_IN +
                             (e & 127) * 4);
  }

  // ---- routing A: emb_out top-2 (wave 0 only)
  if (wid == 0)
    wave_topk<2>(emb_out + task * M1_N, 1, 2, s_m1, lane);
  __syncthreads();

  // ---- park x tile in LDS (loads have drained under routing A)
#pragma unroll
  for (int i = 0; i < 8; ++i) {
    const int e = tid + i * 256;
    *(float4*)(xt + (e >> 7) * XPITCH + (e & 127) * 4) = xr[i];
  }

  // ---- routing B: emb1 top-8 for the 2 selected layer-1 modules
  if (wid < 2)
    wave_topk<2>(emb1 + (size_t)task * M0_N * M1_N + s_m1[wid], M1_N, K_TOP,
                 s_m0 + wid * 8, lane);
  __syncthreads();

  // ---- routing C: emb0 top-8 for the 16 slots, 4 per wave
  for (int s = wid; s < 16; s += 4)
    wave_topk<8>(emb0 + (size_t)task * D_IN * M0_N + s_m0[s], M0_N, K_TOP,
                 s_cols + s * 8, lane);
  __syncthreads();

  const int g  = tid & 31;              // h-group: units 4g..4g+3
  const int rl = tid >> 5;              // row pair
  const int r0 = rl * 2, r1 = r0 + 1;

  // ---- layer 0: 16 slots, weights straight from L2 (coalesced per k)
#pragma unroll 2
  for (int s = 0; s < 16; ++s) {
    const int m0 = s_m0[s];
    const float4* w1p = (const float4*)(W1_0 + (size_t)m0 * (K_TOP * H_DIM));
    float4 w1v[8];
#pragma unroll
    for (int k = 0; k < 8; ++k) w1v[k] = w1p[k * 32 + g];
    const float4 b1v = ((const float4*)(b1_0 + m0 * H_DIM))[g];
    const float4 w2v = ((const float4*)(W2_0 + m0 * H_DIM))[g];
    const float  b2v = b2_0[m0];

    int cols[8];
#pragma unroll
    for (int k = 0; k < 8; ++k) cols[k] = s_cols[s * 8 + k];
    float xv0[8], xv1[8];
#pragma unroll
    for (int k = 0; k < 8; ++k) {
      xv0[k] = xt[r0 * XPITCH + cols[k]];
      xv1[k] = xt[r1 * XPITCH + cols[k]];
    }
    float4 h0 = b1v, h1 = b1v;
#pragma unroll
    for (int k = 0; k < 8; ++k) {
      h0.x = fmaf(xv0[k], w1v[k].x, h0.x);
      h0.y = fmaf(xv0[k], w1v[k].y, h0.y);
      h0.z = fmaf(xv0[k], w1v[k].z, h0.z);
      h0.w = fmaf(xv0[k], w1v[k].w, h0.w);
      h1.x = fmaf(xv1[k], w1v[k].x, h1.x);
      h1.y = fmaf(xv1[k], w1v[k].y, h1.y);
      h1.z = fmaf(xv1[k], w1v[k].z, h1.z);
      h1.w = fmaf(xv1[k], w1v[k].w, h1.w);
    }
    float p0 = 0.f, p1 = 0.f;
    p0 = fmaf(fmaxf(h0.x, 0.f), w2v.x, p0);
    p0 = fmaf(fmaxf(h0.y, 0.f), w2v.y, p0);
    p0 = fmaf(fmaxf(h0.z, 0.f), w2v.z, p0);
    p0 = fmaf(fmaxf(h0.w, 0.f), w2v.w, p0);
    p1 = fmaf(fmaxf(h1.x, 0.f), w2v.x, p1);
    p1 = fmaf(fmaxf(h1.y, 0.f), w2v.y, p1);
    p1 = fmaf(fmaxf(h1.z, 0.f), w2v.z, p1);
    p1 = fmaf(fmaxf(h1.w, 0.f), w2v.w, p1);
#pragma unroll
    for (int m = 1; m < 32; m <<= 1) {
      p0 += __shfl_xor(p0, m, 64);
      p1 += __shfl_xor(p1, m, 64);
    }
    if (g == 0) {
      tile[s * 18 + r0] = p0 + b2v;
      tile[s * 18 + r1] = p1 + b2v;
    }
  }
  __syncthreads();

  // ---- layer 1 (2 modules) + sigmoid
#pragma unroll
  for (int j = 0; j < 2; ++j) {
    const int m1 = s_m1[j];
    const float4* w1p = (const float4*)(W1_1 + (size_t)m1 * (K_TOP * H_DIM));
    float4 w1v[8];
#pragma unroll
    for (int k = 0; k < 8; ++k) w1v[k] = w1p[k * 32 + g];
    const float4 b1v = ((const float4*)(b1_1 + m1 * H_DIM))[g];
    const float4 w2v = ((const float4*)(W2_1 + m1 * H_DIM))[g];
    const float  b2v = b2_1[m1];

    float xv0[8], xv1[8];
#pragma unroll
    for (int k = 0; k < 8; ++k) {
      xv0[k] = tile[(j * 8 + k) * 18 + r0];
      xv1[k] = tile[(j * 8 + k) * 18 + r1];
    }
    float4 h0 = b1v, h1 = b1v;
#pragma unroll
    for (int k = 0; k < 8; ++k) {
      h0.x = fmaf(xv0[k], w1v[k].x, h0.x);
      h0.y = fmaf(xv0[k], w1v[k].y, h0.y);
      h0.z = fmaf(xv0[k], w1v[k].z, h0.z);
      h0.w = fmaf(xv0[k], w1v[k].w, h0.w);
      h1.x = fmaf(xv1[k], w1v[k].x, h1.x);
      h1.y = fmaf(xv1[k], w1v[k].y, h1.y);
      h1.z = fmaf(xv1[k], w1v[k].z, h1.z);
      h1.w = fmaf(xv1[k], w1v[k].w, h1.w);
    }
    float p0 = 0.f, p1 = 0.f;
    p0 = fmaf(fmaxf(h0.x, 0.f), w2v.x, p0);
    p0 = fmaf(fmaxf(h0.y, 0.f), w2v.y, p0);
    p0 = fmaf(fmaxf(h0.z, 0.f), w2v.z, p0);
    p0 = fmaf(fmaxf(h0.w, 0.f), w2v.w, p0);
    p1 = fmaf(fmaxf(h1.x, 0.f), w2v.x, p1);
    p1 = fmaf(fmaxf(h1.y, 0.f), w2v.y, p1);
    p1 = fmaf(fmaxf(h1.z, 0.f), w2v.z, p1);
    p1 = fmaf(fmaxf(h1.w, 0.f), w2v.w, p1);
#pragma unroll
    for (int m = 1; m < 32; m <<= 1) {
      p0 += __shfl_xor(p0, m, 64);
      p1 += __shfl_xor(p1, m, 64);
    }
    if (g == 0) {
      const float v0 = p0 + b2v;
      const float v1 = p1 + b2v;
      out[(size_t)(rowbase + r0) * 2 + j] = 1.f / (1.f + __expf(-v0));
      out[(size_t)(rowbase + r1) * 2 + j] = 1.f / (1.f + __expf(-v1));
    }
  }
}

// ---------------------------------------------------------------------------
extern "C" void kernel_launch(void* const* d_in, const int* in_sizes, int n_in,
                              void* d_out, int out_size, void* d_ws, size_t ws_size,
                              hipStream_t stream) {
  const float* x       = (const float*)d_in[0];
  const int*   task_id = (const int*)  d_in[1];
  const float* emb0    = (const float*)d_in[2];
  const float* emb1    = (const float*)d_in[3];
  const float* emb_out = (const float*)d_in[4];
  const float* W1_0    = (const float*)d_in[5];
  const float* b1_0    = (const float*)d_in[6];
  const float* W2_0    = (const float*)d_in[7];
  const float* b2_0    = (const float*)d_in[8];
  const float* W1_1    = (const float*)d_in[9];
  const float* b1_1    = (const float*)d_in[10];
  const float* W2_1    = (const float*)d_in[11];
  const float* b2_1    = (const float*)d_in[12];

  fused_all<<<B_SZ / ROWS, 256, 0, stream>>>(x, task_id, emb0, emb1, emb_out,
                                             W1_0, b1_0, W2_0, b2_0,
                                             W1_1, b1_1, W2_1, b2_1,
                                             (float*)d_out);
}

// Round 5
// 30.474 us; speedup vs baseline: 2.0061x; 2.0061x over previous
//
#include <hip/hip_runtime.h>
#include <math.h>

// Problem constants
#define B_SZ   8192
#define D_IN   512
#define M0_N   128
#define M1_N   128
#define K_TOP  8
#define H_DIM  128
#define ROWS   16          // batch rows per compute block

// ws layout (ints):
//   [0..1]       idx_out  (top-2 modules of emb_out)
//   [64..1087]   pre1[col*8+r] : top-8 of emb1[task][:,col], all 128 cols
//   [2048..3071] pre0[col*8+r] : top-8 of emb0[task][:,col], all 128 cols

// ---------------------------------------------------------------------------
// Wave-parallel iterative top-k, jax.lax.top_k semantics (descending value,
// ties -> lowest index). NCH*64 candidates; lane 0 writes out_idx.
template<int NCH>
__device__ __forceinline__ void wave_topk(const float* __restrict__ base,
                                          int stride, int k, int* out_idx,
                                          int lane) {
  float v[NCH];
#pragma unroll
  for (int t = 0; t < NCH; ++t) v[t] = base[(t * 64 + lane) * stride];
  for (int r = 0; r < k; ++r) {
    float bv = -INFINITY;
    int bd = 0x7fffffff;
#pragma unroll
    for (int t = 0; t < NCH; ++t) {
      if (v[t] > bv) { bv = v[t]; bd = t * 64 + lane; }
    }
#pragma unroll
    for (int m = 1; m < 64; m <<= 1) {
      float ov = __shfl_xor(bv, m, 64);
      int   od = __shfl_xor(bd, m, 64);
      if (ov > bv || (ov == bv && od < bd)) { bv = ov; bd = od; }
    }
    if (lane == 0) out_idx[r] = bd;
    if ((bd & 63) == lane) {
      const int tw = bd >> 6;
#pragma unroll
      for (int tt = 0; tt < NCH; ++tt)
        if (tt == tw) v[tt] = -INFINITY;
    }
  }
}

// ---------------------------------------------------------------------------
// Speculative routing: top-8 for ALL columns of emb1 and emb0, spread across
// 256 waves chip-wide (one column per wave). Block(0,0) wave 0 also does the
// emb_out top-2. Total work == what one block of round-4 wasted per block.
__global__ __launch_bounds__(256)
void route_pre(const int* __restrict__ task_id_p,
               const float* __restrict__ emb0,
               const float* __restrict__ emb1,
               const float* __restrict__ emb_out,
               int* __restrict__ ws) {
  const int task = task_id_p[0];
  const int lane = threadIdx.x & 63;
  const int wid  = threadIdx.x >> 6;
  const int col  = blockIdx.x * 4 + wid;
  if (blockIdx.y == 0) {
    wave_topk<2>(emb1 + (size_t)task * M0_N * M1_N + col, M1_N, K_TOP,
                 ws + 64 + col * 8, lane);
    if (blockIdx.x == 0 && wid == 0)
      wave_topk<2>(emb_out + task * M1_N, 1, 2, ws, lane);
  } else {
    wave_topk<8>(emb0 + (size_t)task * D_IN * M0_N + col, M0_N, K_TOP,
                 ws + 2048 + col * 8, lane);
  }
}

// ---------------------------------------------------------------------------
// Fused compute: layer0 (16 positional slots) + layer1 (2 modules) + sigmoid.
// Routing read from ws (3 short dependent loads). Thread (g=tid&31, rl=tid>>5)
// owns hidden units 4g..4g+3 of rows {2rl, 2rl+1}; 32-lane shfl_xor reduce.
// x gathered directly from global: per load instruction the 32 g-lanes share
// one address (2 transactions/wave); weights coalesced float4 per wave.
__global__ __launch_bounds__(256)
void fused_compute(const float* __restrict__ x,
                   const float* __restrict__ W1_0, const float* __restrict__ b1_0,
                   const float* __restrict__ W2_0, const float* __restrict__ b2_0,
                   const float* __restrict__ W1_1, const float* __restrict__ b1_1,
                   const float* __restrict__ W2_1, const float* __restrict__ b2_1,
                   const int* __restrict__ ws, float* __restrict__ out) {
  __shared__ int   s_m1[2];
  __shared__ int   s_m0[16];
  __shared__ int   s_cols[128];
  __shared__ float tile[16 * 18];       // layer-0 outputs [slot][row]

  const int tid = threadIdx.x;
  const int rowbase = blockIdx.x * ROWS;

  // resolve routing indirection (3 dependent rounds, L2-broadcast)
  if (tid < 2) s_m1[tid] = ws[tid];
  __syncthreads();
  if (tid < 16) s_m0[tid] = ws[64 + s_m1[tid >> 3] * 8 + (tid & 7)];
  __syncthreads();
  if (tid < 128) s_cols[tid] = ws[2048 + s_m0[tid >> 3] * 8 + (tid & 7)];
  __syncthreads();

  const int g  = tid & 31;              // h-group: units 4g..4g+3
  const int rl = tid >> 5;              // row pair 0..7
  const int r0 = rl * 2, r1 = r0 + 1;
  const float* xr0 = x + (size_t)(rowbase + r0) * D_IN;
  const float* xr1 = x + (size_t)(rowbase + r1) * D_IN;

  // ---- layer 0: 16 slots ----
  for (int s = 0; s < 16; ++s) {
    const int m0 = s_m0[s];
    const float4* w1p = (const float4*)(W1_0 + (size_t)m0 * (K_TOP * H_DIM));
    float4 w1v[8];
#pragma unroll
    for (int k = 0; k < 8; ++k) w1v[k] = w1p[k * 32 + g];
    const float4 b1v = ((const float4*)(b1_0 + m0 * H_DIM))[g];
    const float4 w2v = ((const float4*)(W2_0 + m0 * H_DIM))[g];
    const float  b2v = b2_0[m0];

    float xv0[8], xv1[8];
#pragma unroll
    for (int k = 0; k < 8; ++k) {
      const int c = s_cols[s * 8 + k];
      xv0[k] = xr0[c];
      xv1[k] = xr1[c];
    }
    float4 h0 = b1v, h1 = b1v;
#pragma unroll
    for (int k = 0; k < 8; ++k) {
      h0.x = fmaf(xv0[k], w1v[k].x, h0.x);
      h0.y = fmaf(xv0[k], w1v[k].y, h0.y);
      h0.z = fmaf(xv0[k], w1v[k].z, h0.z);
      h0.w = fmaf(xv0[k], w1v[k].w, h0.w);
      h1.x = fmaf(xv1[k], w1v[k].x, h1.x);
      h1.y = fmaf(xv1[k], w1v[k].y, h1.y);
      h1.z = fmaf(xv1[k], w1v[k].z, h1.z);
      h1.w = fmaf(xv1[k], w1v[k].w, h1.w);
    }
    float p0 = 0.f, p1 = 0.f;
    p0 = fmaf(fmaxf(h0.x, 0.f), w2v.x, p0);
    p0 = fmaf(fmaxf(h0.y, 0.f), w2v.y, p0);
    p0 = fmaf(fmaxf(h0.z, 0.f), w2v.z, p0);
    p0 = fmaf(fmaxf(h0.w, 0.f), w2v.w, p0);
    p1 = fmaf(fmaxf(h1.x, 0.f), w2v.x, p1);
    p1 = fmaf(fmaxf(h1.y, 0.f), w2v.y, p1);
    p1 = fmaf(fmaxf(h1.z, 0.f), w2v.z, p1);
    p1 = fmaf(fmaxf(h1.w, 0.f), w2v.w, p1);
#pragma unroll
    for (int m = 1; m < 32; m <<= 1) {
      p0 += __shfl_xor(p0, m, 64);
      p1 += __shfl_xor(p1, m, 64);
    }
    if (g == 0) {
      tile[s * 18 + r0] = p0 + b2v;
      tile[s * 18 + r1] = p1 + b2v;
    }
  }
  __syncthreads();

  // ---- layer 1 (2 modules) + sigmoid ----
#pragma unroll
  for (int j = 0; j < 2; ++j) {
    const int m1 = s_m1[j];
    const float4* w1p = (const float4*)(W1_1 + (size_t)m1 * (K_TOP * H_DIM));
    float4 w1v[8];
#pragma unroll
    for (int k = 0; k < 8; ++k) w1v[k] = w1p[k * 32 + g];
    const float4 b1v = ((const float4*)(b1_1 + m1 * H_DIM))[g];
    const float4 w2v = ((const float4*)(W2_1 + m1 * H_DIM))[g];
    const float  b2v = b2_1[m1];

    float xv0[8], xv1[8];
#pragma unroll
    for (int k = 0; k < 8; ++k) {
      xv0[k] = tile[(j * 8 + k) * 18 + r0];
      xv1[k] = tile[(j * 8 + k) * 18 + r1];
    }
    float4 h0 = b1v, h1 = b1v;
#pragma unroll
    for (int k = 0; k < 8; ++k) {
      h0.x = fmaf(xv0[k], w1v[k].x, h0.x);
      h0.y = fmaf(xv0[k], w1v[k].y, h0.y);
      h0.z = fmaf(xv0[k], w1v[k].z, h0.z);
      h0.w = fmaf(xv0[k], w1v[k].w, h0.w);
      h1.x = fmaf(xv1[k], w1v[k].x, h1.x);
      h1.y = fmaf(xv1[k], w1v[k].y, h1.y);
      h1.z = fmaf(xv1[k], w1v[k].z, h1.z);
      h1.w = fmaf(xv1[k], w1v[k].w, h1.w);
    }
    float p0 = 0.f, p1 = 0.f;
    p0 = fmaf(fmaxf(h0.x, 0.f), w2v.x, p0);
    p0 = fmaf(fmaxf(h0.y, 0.f), w2v.y, p0);
    p0 = fmaf(fmaxf(h0.z, 0.f), w2v.z, p0);
    p0 = fmaf(fmaxf(h0.w, 0.f), w2v.w, p0);
    p1 = fmaf(fmaxf(h1.x, 0.f), w2v.x, p1);
    p1 = fmaf(fmaxf(h1.y, 0.f), w2v.y, p1);
    p1 = fmaf(fmaxf(h1.z, 0.f), w2v.z, p1);
    p1 = fmaf(fmaxf(h1.w, 0.f), w2v.w, p1);
#pragma unroll
    for (int m = 1; m < 32; m <<= 1) {
      p0 += __shfl_xor(p0, m, 64);
      p1 += __shfl_xor(p1, m, 64);
    }
    if (g == 0) {
      const float v0 = p0 + b2v;
      const float v1 = p1 + b2v;
      out[(size_t)(rowbase + r0) * 2 + j] = 1.f / (1.f + __expf(-v0));
      out[(size_t)(rowbase + r1) * 2 + j] = 1.f / (1.f + __expf(-v1));
    }
  }
}

// ---------------------------------------------------------------------------
extern "C" void kernel_launch(void* const* d_in, const int* in_sizes, int n_in,
                              void* d_out, int out_size, void* d_ws, size_t ws_size,
                              hipStream_t stream) {
  const float* x       = (const float*)d_in[0];
  const int*   task_id = (const int*)  d_in[1];
  const float* emb0    = (const float*)d_in[2];
  const float* emb1    = (const float*)d_in[3];
  const float* emb_out = (const float*)d_in[4];
  const float* W1_0    = (const float*)d_in[5];
  const float* b1_0    = (const float*)d_in[6];
  const float* W2_0    = (const float*)d_in[7];
  const float* b2_0    = (const float*)d_in[8];
  const float* W1_1    = (const float*)d_in[9];
  const float* b1_1    = (const float*)d_in[10];
  const float* W2_1    = (const float*)d_in[11];
  const float* b2_1    = (const float*)d_in[12];

  int* ws = (int*)d_ws;

  route_pre<<<dim3(32, 2), 256, 0, stream>>>(task_id, emb0, emb1, emb_out, ws);
  fused_compute<<<B_SZ / ROWS, 256, 0, stream>>>(x, W1_0, b1_0, W2_0, b2_0,
                                                 W1_1, b1_1, W2_1, b2_1,
                                                 ws, (float*)d_out);
}